// Round 4
// baseline (3214.098 us; speedup 1.0000x reference)
//
#include <hip/hip_runtime.h>
#include <math.h>

#define BS   2048
#define SEQ  50
#define NPOS (BS * SEQ)

__device__ __forceinline__ float sigf(float x) { return 1.0f / (1.0f + __expf(-x)); }
__device__ __forceinline__ float tanhfast(float x) {
    float e = __expf(2.0f * x);
    return 1.0f - 2.0f / (e + 1.0f);
}

// ---- macro toolkit: named-SSA weight residency (NO private arrays) --------
#define FMA4(A, X, W) \
    A = fmaf((X).x, (W).x, A); A = fmaf((X).y, (W).y, A); \
    A = fmaf((X).z, (W).z, A); A = fmaf((X).w, (W).w, A);

#define LD16(P, N) \
    float4 N##0=(P)[0],  N##1=(P)[1],  N##2=(P)[2],  N##3=(P)[3], \
           N##4=(P)[4],  N##5=(P)[5],  N##6=(P)[6],  N##7=(P)[7], \
           N##8=(P)[8],  N##9=(P)[9],  N##10=(P)[10],N##11=(P)[11], \
           N##12=(P)[12],N##13=(P)[13],N##14=(P)[14],N##15=(P)[15];

// ---------------------------------------------------------------------------
// Kernel A: edge fusion + masked multi-head attention -> ctx[BS][SEQ][64]
// (unchanged from R3 — ~300 us; lstm is the target this round)
// ---------------------------------------------------------------------------
__global__ __launch_bounds__(64, 1) void edge_attn_ctx(
    const float* __restrict__ seqs,   // [BS,SEQ,3,3,6]
    const float* __restrict__ ets,    // [BS,SEQ,3,3,4]
    const int*   __restrict__ masks,  // [BS,SEQ,3,3]
    const float* __restrict__ Wf, const float* __restrict__ bf,  // [64,19],[64]
    const float* __restrict__ Wk, const float* __restrict__ bk,  // [64,6],[64]
    const float* __restrict__ Wq, const float* __restrict__ bq,  // [64,64],[64]
    const float* __restrict__ Wv, const float* __restrict__ bv,  // [64,64],[64]
    float* __restrict__ ctx)          // [BS,SEQ,64]
{
    const int o = threadIdx.x;

    const float4* qp = (const float4*)&Wq[o * 64];
    LD16(qp, wq)
    const float4* vp = (const float4*)&Wv[o * 64];
    LD16(vp, wv)

    const float* wfp = &Wf[o * 19];
    float wf0=wfp[0], wf1=wfp[1], wf2=wfp[2], wf3=wfp[3], wf4=wfp[4], wf5=wfp[5],
          wf6=wfp[6], wf7=wfp[7], wf8=wfp[8], wf9=wfp[9];
    float wfe0=wfp[10], wfe1=wfp[11], wfe2=wfp[12], wfe3=wfp[13], wfe4=wfp[14],
          wfe5=wfp[15], wfe6=wfp[16], wfe7=wfp[17], wfe8=wfp[18];
    const float* wkp = &Wk[o * 6];
    float wk0=wkp[0], wk1=wkp[1], wk2=wkp[2], wk3=wkp[3], wk4=wkp[4], wk5=wkp[5];

    const float bfr = bf[o], bkr = bk[o], bqr = bq[o], bvr = bv[o];

    __shared__ float s_seq[54];
    __shared__ float s_et[36];
    __shared__ int   s_mask[9];
    __shared__ float s_edge[9 * 64];

    for (int p = blockIdx.x; p < NPOS; p += gridDim.x) {
        if (o < 54) s_seq[o]  = seqs[p * 54 + o];
        if (o < 36) s_et[o]   = ets[p * 36 + o];
        if (o < 9)  s_mask[o] = masks[p * 9 + o];
        __syncthreads();

        float wfe[9] = {wfe0,wfe1,wfe2,wfe3,wfe4,wfe5,wfe6,wfe7,wfe8};
        #pragma unroll
        for (int e = 0; e < 9; ++e) {
            float v = bfr + wfe[e];
            v = fmaf(s_seq[e*6+0], wf0, v);
            v = fmaf(s_seq[e*6+1], wf1, v);
            v = fmaf(s_seq[e*6+2], wf2, v);
            v = fmaf(s_seq[e*6+3], wf3, v);
            v = fmaf(s_seq[e*6+4], wf4, v);
            v = fmaf(s_seq[e*6+5], wf5, v);
            v = fmaf(s_et[e*4+0],  wf6, v);
            v = fmaf(s_et[e*4+1],  wf7, v);
            v = fmaf(s_et[e*4+2],  wf8, v);
            v = fmaf(s_et[e*4+3],  wf9, v);
            s_edge[e * 64 + o] = v;
        }
        float key = bkr;
        key = fmaf(s_seq[24], wk0, key);
        key = fmaf(s_seq[25], wk1, key);
        key = fmaf(s_seq[26], wk2, key);
        key = fmaf(s_seq[27], wk3, key);
        key = fmaf(s_seq[28], wk4, key);
        key = fmaf(s_seq[29], wk5, key);
        __syncthreads();

        float vv[9], att[9];
        #pragma unroll
        for (int e = 0; e < 9; ++e) {
            const float4* ep = (const float4*)&s_edge[e * 64];
            float q = 0.f, v = 0.f;
            {
                float4 t;
                t=ep[0];  FMA4(q,t,wq0)  FMA4(v,t,wv0)
                t=ep[1];  FMA4(q,t,wq1)  FMA4(v,t,wv1)
                t=ep[2];  FMA4(q,t,wq2)  FMA4(v,t,wv2)
                t=ep[3];  FMA4(q,t,wq3)  FMA4(v,t,wv3)
                t=ep[4];  FMA4(q,t,wq4)  FMA4(v,t,wv4)
                t=ep[5];  FMA4(q,t,wq5)  FMA4(v,t,wv5)
                t=ep[6];  FMA4(q,t,wq6)  FMA4(v,t,wv6)
                t=ep[7];  FMA4(q,t,wq7)  FMA4(v,t,wv7)
                t=ep[8];  FMA4(q,t,wq8)  FMA4(v,t,wv8)
                t=ep[9];  FMA4(q,t,wq9)  FMA4(v,t,wv9)
                t=ep[10]; FMA4(q,t,wq10) FMA4(v,t,wv10)
                t=ep[11]; FMA4(q,t,wq11) FMA4(v,t,wv11)
                t=ep[12]; FMA4(q,t,wq12) FMA4(v,t,wv12)
                t=ep[13]; FMA4(q,t,wq13) FMA4(v,t,wv13)
                t=ep[14]; FMA4(q,t,wq14) FMA4(v,t,wv14)
                t=ep[15]; FMA4(q,t,wq15) FMA4(v,t,wv15)
            }
            float qq = bqr + q;
            vv[e] = bvr + v;
            float a_ = key * qq;
            a_ += __shfl_xor(a_, 8, 16);
            a_ += __shfl_xor(a_, 4, 16);
            a_ += __shfl_xor(a_, 2, 16);
            a_ += __shfl_xor(a_, 1, 16);
            att[e] = a_ * 0.25f;   // / sqrt(16)
        }

        float mx = -3.0e38f;
        #pragma unroll
        for (int e = 0; e < 9; ++e) {
            att[e] = (s_mask[e] == 0) ? -1.0e10f : att[e];
            mx = fmaxf(mx, att[e]);
        }
        float ssum = 0.f;
        #pragma unroll
        for (int e = 0; e < 9; ++e) { att[e] = __expf(att[e] - mx); ssum += att[e]; }
        float inv = 1.f / ssum;
        float acc = 0.f;
        #pragma unroll
        for (int e = 0; e < 9; ++e) acc = fmaf(att[e], vv[e], acc);
        ctx[p * 64 + o] = acc * inv;
        __syncthreads();
    }
}

// ---------------------------------------------------------------------------
// Kernel C v3: LSTM fitted UNDER the 128-VGPR budget (the compiler forces 128
// for big blocks; R1-R3 all spilled). 1024 threads (16 waves -> 128 is also
// the structural ceiling), 512 blocks x 4 batch rows.
//   matmul:  thread t: gg=t>>2 (gate pair j0=2gg), kh=t&3 (k-chunk).
//            weights = 2 gates x (16 x-cols + 32 h-cols) = 24 float4 = 96 VGPR.
//            partial sums reduced over kh via 2x shfl_xor (DPP, no LDS).
//   pointwise: t<512 -> (row pr=t>>7, m=t&127), c-state in register.
//   s_h bank-skew: chunk kc starts at kc*36 floats so the 4 kh readers hit
//   disjoint bank groups (unskewed -> 4-way conflict = 1.58x per m136).
// ---------------------------------------------------------------------------
#define HROW 144   // 4 chunks * 36 floats

#define ROWX(r, A0, A1) { \
    const float4* xp_ = (const float4*)(xbase + (r)*64); \
    float4 q_; \
    q_=xp_[0]; FMA4(A0,q_,xa0) FMA4(A1,q_,xb0) \
    q_=xp_[1]; FMA4(A0,q_,xa1) FMA4(A1,q_,xb1) \
    q_=xp_[2]; FMA4(A0,q_,xa2) FMA4(A1,q_,xb2) \
    q_=xp_[3]; FMA4(A0,q_,xa3) FMA4(A1,q_,xb3) }

#define ROWH(r, A0, A1) { \
    const float4* hp_ = (const float4*)(hbase + (r)*HROW); \
    float4 q_; \
    q_=hp_[0]; FMA4(A0,q_,ha0) FMA4(A1,q_,hb0) \
    q_=hp_[1]; FMA4(A0,q_,ha1) FMA4(A1,q_,hb1) \
    q_=hp_[2]; FMA4(A0,q_,ha2) FMA4(A1,q_,hb2) \
    q_=hp_[3]; FMA4(A0,q_,ha3) FMA4(A1,q_,hb3) \
    q_=hp_[4]; FMA4(A0,q_,ha4) FMA4(A1,q_,hb4) \
    q_=hp_[5]; FMA4(A0,q_,ha5) FMA4(A1,q_,hb5) \
    q_=hp_[6]; FMA4(A0,q_,ha6) FMA4(A1,q_,hb6) \
    q_=hp_[7]; FMA4(A0,q_,ha7) FMA4(A1,q_,hb7) }

#define RED(A) A += __shfl_xor(A, 1); A += __shfl_xor(A, 2);

__global__ __launch_bounds__(1024) void lstm_out(
    const float* __restrict__ ctx,    // [BS,SEQ,64]
    const float* __restrict__ W_ih,   // [512,64]
    const float* __restrict__ W_hh,   // [512,128]
    const float* __restrict__ b_ih, const float* __restrict__ b_hh,
    const float* __restrict__ W_out,  // [64,128]
    const float* __restrict__ b_out,  // [64]
    float* __restrict__ out)          // [BS,64]
{
    const int t    = threadIdx.x;
    const int gg   = t >> 2;          // 0..255 -> gates 2gg, 2gg+1
    const int kh   = t & 3;           // k-chunk 0..3
    const int j0   = gg * 2;
    const int row0 = blockIdx.x * 4;

    // ---- weight residency: 24 float4 = 96 VGPR, named SSA ----
    const float4* xap = (const float4*)&W_ih[j0 * 64 + kh * 16];
    float4 xa0=xap[0], xa1=xap[1], xa2=xap[2], xa3=xap[3];
    const float4* xbp = (const float4*)&W_ih[(j0 + 1) * 64 + kh * 16];
    float4 xb0=xbp[0], xb1=xbp[1], xb2=xbp[2], xb3=xbp[3];
    const float4* hap = (const float4*)&W_hh[j0 * 128 + kh * 32];
    float4 ha0=hap[0], ha1=hap[1], ha2=hap[2], ha3=hap[3],
           ha4=hap[4], ha5=hap[5], ha6=hap[6], ha7=hap[7];
    const float4* hbp = (const float4*)&W_hh[(j0 + 1) * 128 + kh * 32];
    float4 hb0=hbp[0], hb1=hbp[1], hb2=hbp[2], hb3=hbp[3],
           hb4=hbp[4], hb5=hbp[5], hb6=hbp[6], hb7=hbp[7];

    // ---- pointwise role (t < 512): biases held in 4 regs ----
    const int pr = (t >> 7) & 3;
    const int pm = t & 127;
    float bi = 0.f, bff = 0.f, bgg = 0.f, boo = 0.f;
    if (t < 512) {
        bi  = b_ih[pm]        + b_hh[pm];
        bff = b_ih[128 + pm]  + b_hh[128 + pm];
        bgg = b_ih[256 + pm]  + b_hh[256 + pm];
        boo = b_ih[384 + pm]  + b_hh[384 + pm];
    }

    __shared__ float s_x[4 * 64];     // [r][c]
    __shared__ float s_h[4 * HROW];   // bank-skewed hidden state
    __shared__ float s_g[4 * 512];    // pre-activation gates

    const float* xbase = &s_x[kh * 16];
    const float* hbase = &s_h[kh * 36];

    float c = 0.f;

    // prologue: stage x for s=0
    if (t < 256) s_x[t] = ctx[(row0 + (t >> 6)) * (SEQ * 64) + (t & 63)];
    __syncthreads();

    for (int s = 0; s < SEQ; ++s) {
        float a00=0.f, a01=0.f, a02=0.f, a03=0.f;   // gate j0, rows 0..3
        float a10=0.f, a11=0.f, a12=0.f, a13=0.f;   // gate j0+1

        ROWX(0, a00, a10) ROWX(1, a01, a11) ROWX(2, a02, a12) ROWX(3, a03, a13)
        if (s > 0) {
            ROWH(0, a00, a10) ROWH(1, a01, a11) ROWH(2, a02, a12) ROWH(3, a03, a13)
        }

        RED(a00) RED(a01) RED(a02) RED(a03)
        RED(a10) RED(a11) RED(a12) RED(a13)

        // lane kh writes batch-row kh's gate pair (one ds_write_b64)
        float g0 = (kh == 0) ? a00 : (kh == 1) ? a01 : (kh == 2) ? a02 : a03;
        float g1 = (kh == 0) ? a10 : (kh == 1) ? a11 : (kh == 2) ? a12 : a13;
        *(float2*)&s_g[kh * 512 + j0] = make_float2(g0, g1);
        __syncthreads();

        if (t < 512) {
            float ig = sigf(s_g[pr * 512 + pm] + bi);
            float fg = sigf(s_g[pr * 512 + 128 + pm] + bff);
            float gt = tanhfast(s_g[pr * 512 + 256 + pm] + bgg);
            float og = sigf(s_g[pr * 512 + 384 + pm] + boo);
            c = fmaf(fg, c, ig * gt);
            s_h[pr * HROW + pm + ((pm >> 5) << 2)] = og * tanhfast(c);
        } else if (t < 768 && s + 1 < SEQ) {
            int tt = t - 512;
            s_x[tt] = ctx[(row0 + (tt >> 6)) * (SEQ * 64) + (s + 1) * 64 + (tt & 63)];
        }
        __syncthreads();
    }

    // epilogue: out[row0+r][o] = b_out[o] + h[r] . W_out[o]
    if (t < 256) {
        int r = t >> 6, o = t & 63;
        float acc = b_out[o];
        const float4* wp = (const float4*)&W_out[o * 128];
        #pragma unroll
        for (int kc = 0; kc < 4; ++kc) {
            #pragma unroll
            for (int i = 0; i < 8; ++i) {
                float4 h4 = *(const float4*)&s_h[r * HROW + kc * 36 + i * 4];
                float4 w4 = wp[kc * 8 + i];
                FMA4(acc, h4, w4)
            }
        }
        out[(row0 + r) * 64 + o] = acc;
    }
}

// ---------------------------------------------------------------------------
extern "C" void kernel_launch(void* const* d_in, const int* in_sizes, int n_in,
                              void* d_out, int out_size, void* d_ws, size_t ws_size,
                              hipStream_t stream) {
    (void)in_sizes; (void)n_in; (void)out_size; (void)ws_size;
    const float* seqs  = (const float*)d_in[0];
    const float* ets   = (const float*)d_in[1];
    const int*   masks = (const int*)d_in[2];
    const float* Wf  = (const float*)d_in[3];
    const float* bf  = (const float*)d_in[4];
    const float* Wk  = (const float*)d_in[5];
    const float* bk  = (const float*)d_in[6];
    const float* Wq  = (const float*)d_in[7];
    const float* bq  = (const float*)d_in[8];
    const float* Wv  = (const float*)d_in[9];
    const float* bv  = (const float*)d_in[10];
    const float* Wih = (const float*)d_in[11];
    const float* Whh = (const float*)d_in[12];
    const float* bih = (const float*)d_in[13];
    const float* bhh = (const float*)d_in[14];
    const float* Wo  = (const float*)d_in[15];
    const float* bo  = (const float*)d_in[16];

    float* ctx = (float*)d_ws;  // [BS,SEQ,64] fp32 = 26.2 MB

    hipLaunchKernelGGL(edge_attn_ctx, dim3(4096), dim3(64), 0, stream,
                       seqs, ets, masks, Wf, bf, Wk, bk, Wq, bq, Wv, bv, ctx);
    hipLaunchKernelGGL(lstm_out, dim3(512), dim3(1024), 0, stream,
                       ctx, Wih, Whh, bih, bhh, Wo, bo, (float*)d_out);
}

// Round 5
// 2754.603 us; speedup vs baseline: 1.1668x; 1.1668x over previous
//
#include <hip/hip_runtime.h>
#include <math.h>

#define BS   2048
#define SEQ  50
#define NPOS (BS * SEQ)

__device__ __forceinline__ float sigf(float x) { return 1.0f / (1.0f + __expf(-x)); }
__device__ __forceinline__ float tanhfast(float x) {
    float e = __expf(2.0f * x);
    return 1.0f - 2.0f / (e + 1.0f);
}

// ---- macro toolkit: named-SSA weight residency (NO private arrays) --------
#define FMA4(A, X, W) \
    A = fmaf((X).x, (W).x, A); A = fmaf((X).y, (W).y, A); \
    A = fmaf((X).z, (W).z, A); A = fmaf((X).w, (W).w, A);

#define LD16(P, N) \
    float4 N##0=(P)[0],  N##1=(P)[1],  N##2=(P)[2],  N##3=(P)[3], \
           N##4=(P)[4],  N##5=(P)[5],  N##6=(P)[6],  N##7=(P)[7], \
           N##8=(P)[8],  N##9=(P)[9],  N##10=(P)[10],N##11=(P)[11], \
           N##12=(P)[12],N##13=(P)[13],N##14=(P)[14],N##15=(P)[15];

#define LD32(P, N) LD16(P, N) \
    float4 N##16=(P)[16],N##17=(P)[17],N##18=(P)[18],N##19=(P)[19], \
           N##20=(P)[20],N##21=(P)[21],N##22=(P)[22],N##23=(P)[23], \
           N##24=(P)[24],N##25=(P)[25],N##26=(P)[26],N##27=(P)[27], \
           N##28=(P)[28],N##29=(P)[29],N##30=(P)[30],N##31=(P)[31];

#define DOT16(A, X, W) \
    FMA4(A,(X)[0],W##0)   FMA4(A,(X)[1],W##1)   FMA4(A,(X)[2],W##2)   FMA4(A,(X)[3],W##3) \
    FMA4(A,(X)[4],W##4)   FMA4(A,(X)[5],W##5)   FMA4(A,(X)[6],W##6)   FMA4(A,(X)[7],W##7) \
    FMA4(A,(X)[8],W##8)   FMA4(A,(X)[9],W##9)   FMA4(A,(X)[10],W##10) FMA4(A,(X)[11],W##11) \
    FMA4(A,(X)[12],W##12) FMA4(A,(X)[13],W##13) FMA4(A,(X)[14],W##14) FMA4(A,(X)[15],W##15)

#define DOT32(A, X, W) DOT16(A, X, W) \
    FMA4(A,(X)[16],W##16) FMA4(A,(X)[17],W##17) FMA4(A,(X)[18],W##18) FMA4(A,(X)[19],W##19) \
    FMA4(A,(X)[20],W##20) FMA4(A,(X)[21],W##21) FMA4(A,(X)[22],W##22) FMA4(A,(X)[23],W##23) \
    FMA4(A,(X)[24],W##24) FMA4(A,(X)[25],W##25) FMA4(A,(X)[26],W##26) FMA4(A,(X)[27],W##27) \
    FMA4(A,(X)[28],W##28) FMA4(A,(X)[29],W##29) FMA4(A,(X)[30],W##30) FMA4(A,(X)[31],W##31)

// ---------------------------------------------------------------------------
// Kernel A: edge fusion + masked multi-head attention -> ctx[BS][SEQ][64]
// block = 64 threads (1 wave); lane = output channel o.
// amdgpu_waves_per_eu(2,2): sets the scheduler's occupancy TARGET (the thing
// launch_bounds arg2 failed to move in R1-R4) -> 256-VGPR budget, demand ~170.
// ---------------------------------------------------------------------------
__global__
__attribute__((amdgpu_flat_work_group_size(64, 64), amdgpu_waves_per_eu(2, 2)))
void edge_attn_ctx(
    const float* __restrict__ seqs,   // [BS,SEQ,3,3,6]
    const float* __restrict__ ets,    // [BS,SEQ,3,3,4]
    const int*   __restrict__ masks,  // [BS,SEQ,3,3]
    const float* __restrict__ Wf, const float* __restrict__ bf,  // [64,19],[64]
    const float* __restrict__ Wk, const float* __restrict__ bk,  // [64,6],[64]
    const float* __restrict__ Wq, const float* __restrict__ bq,  // [64,64],[64]
    const float* __restrict__ Wv, const float* __restrict__ bv,  // [64,64],[64]
    float* __restrict__ ctx)          // [BS,SEQ,64]
{
    const int o = threadIdx.x;

    const float4* qp = (const float4*)&Wq[o * 64];
    LD16(qp, wq)
    const float4* vp = (const float4*)&Wv[o * 64];
    LD16(vp, wv)

    const float* wfp = &Wf[o * 19];
    float wf0=wfp[0], wf1=wfp[1], wf2=wfp[2], wf3=wfp[3], wf4=wfp[4], wf5=wfp[5],
          wf6=wfp[6], wf7=wfp[7], wf8=wfp[8], wf9=wfp[9];
    float wfe0=wfp[10], wfe1=wfp[11], wfe2=wfp[12], wfe3=wfp[13], wfe4=wfp[14],
          wfe5=wfp[15], wfe6=wfp[16], wfe7=wfp[17], wfe8=wfp[18];
    const float* wkp = &Wk[o * 6];
    float wk0=wkp[0], wk1=wkp[1], wk2=wkp[2], wk3=wkp[3], wk4=wkp[4], wk5=wkp[5];

    const float bfr = bf[o], bkr = bk[o], bqr = bq[o], bvr = bv[o];

    __shared__ float s_seq[54];
    __shared__ float s_et[36];
    __shared__ int   s_mask[9];
    __shared__ float s_edge[9 * 64];

    for (int p = blockIdx.x; p < NPOS; p += gridDim.x) {
        if (o < 54) s_seq[o]  = seqs[p * 54 + o];
        if (o < 36) s_et[o]   = ets[p * 36 + o];
        if (o < 9)  s_mask[o] = masks[p * 9 + o];
        __syncthreads();

        float wfe[9] = {wfe0,wfe1,wfe2,wfe3,wfe4,wfe5,wfe6,wfe7,wfe8};
        #pragma unroll
        for (int e = 0; e < 9; ++e) {
            float v = bfr + wfe[e];
            v = fmaf(s_seq[e*6+0], wf0, v);
            v = fmaf(s_seq[e*6+1], wf1, v);
            v = fmaf(s_seq[e*6+2], wf2, v);
            v = fmaf(s_seq[e*6+3], wf3, v);
            v = fmaf(s_seq[e*6+4], wf4, v);
            v = fmaf(s_seq[e*6+5], wf5, v);
            v = fmaf(s_et[e*4+0],  wf6, v);
            v = fmaf(s_et[e*4+1],  wf7, v);
            v = fmaf(s_et[e*4+2],  wf8, v);
            v = fmaf(s_et[e*4+3],  wf9, v);
            s_edge[e * 64 + o] = v;
        }
        float key = bkr;
        key = fmaf(s_seq[24], wk0, key);
        key = fmaf(s_seq[25], wk1, key);
        key = fmaf(s_seq[26], wk2, key);
        key = fmaf(s_seq[27], wk3, key);
        key = fmaf(s_seq[28], wk4, key);
        key = fmaf(s_seq[29], wk5, key);
        __syncthreads();

        float vv[9], att[9];
        #pragma unroll
        for (int e = 0; e < 9; ++e) {
            const float4* ep = (const float4*)&s_edge[e * 64];
            float q = 0.f, v = 0.f;
            {
                float4 t;
                t=ep[0];  FMA4(q,t,wq0)  FMA4(v,t,wv0)
                t=ep[1];  FMA4(q,t,wq1)  FMA4(v,t,wv1)
                t=ep[2];  FMA4(q,t,wq2)  FMA4(v,t,wv2)
                t=ep[3];  FMA4(q,t,wq3)  FMA4(v,t,wv3)
                t=ep[4];  FMA4(q,t,wq4)  FMA4(v,t,wv4)
                t=ep[5];  FMA4(q,t,wq5)  FMA4(v,t,wv5)
                t=ep[6];  FMA4(q,t,wq6)  FMA4(v,t,wv6)
                t=ep[7];  FMA4(q,t,wq7)  FMA4(v,t,wv7)
                t=ep[8];  FMA4(q,t,wq8)  FMA4(v,t,wv8)
                t=ep[9];  FMA4(q,t,wq9)  FMA4(v,t,wv9)
                t=ep[10]; FMA4(q,t,wq10) FMA4(v,t,wv10)
                t=ep[11]; FMA4(q,t,wq11) FMA4(v,t,wv11)
                t=ep[12]; FMA4(q,t,wq12) FMA4(v,t,wv12)
                t=ep[13]; FMA4(q,t,wq13) FMA4(v,t,wv13)
                t=ep[14]; FMA4(q,t,wq14) FMA4(v,t,wv14)
                t=ep[15]; FMA4(q,t,wq15) FMA4(v,t,wv15)
            }
            float qq = bqr + q;
            vv[e] = bvr + v;
            float a_ = key * qq;
            a_ += __shfl_xor(a_, 8, 16);
            a_ += __shfl_xor(a_, 4, 16);
            a_ += __shfl_xor(a_, 2, 16);
            a_ += __shfl_xor(a_, 1, 16);
            att[e] = a_ * 0.25f;   // / sqrt(16)
        }

        float mx = -3.0e38f;
        #pragma unroll
        for (int e = 0; e < 9; ++e) {
            att[e] = (s_mask[e] == 0) ? -1.0e10f : att[e];
            mx = fmaxf(mx, att[e]);
        }
        float ssum = 0.f;
        #pragma unroll
        for (int e = 0; e < 9; ++e) { att[e] = __expf(att[e] - mx); ssum += att[e]; }
        float inv = 1.f / ssum;
        float acc = 0.f;
        #pragma unroll
        for (int e = 0; e < 9; ++e) acc = fmaf(att[e], vv[e], acc);
        ctx[p * 64 + o] = acc * inv;
        __syncthreads();
    }
}

// ---------------------------------------------------------------------------
// Kernel C (R3 structure + occupancy pin): 256 blocks x 512 threads, thread j
// holds W_ih[j][:] + W_hh[j][:] as 48 named float4 SSA values (~230 VGPR live).
// amdgpu_waves_per_eu(2,2) -> scheduler occupancy target 2 waves/EU ->
// 256-VGPR budget. R1-R4: default target (4-8 waves/EU) forced 128/64-reg
// budgets and 5-10 GB/dispatch of weight rematerialization traffic.
// ---------------------------------------------------------------------------
#define XP(r) ((const float4*)&s_x[r][0])
#define HP(r) ((const float4*)&s_h[r][0])

__global__
__attribute__((amdgpu_flat_work_group_size(512, 512), amdgpu_waves_per_eu(2, 2)))
void lstm_out(
    const float* __restrict__ ctx,    // [BS,SEQ,64]
    const float* __restrict__ W_ih,   // [512,64]
    const float* __restrict__ W_hh,   // [512,128]
    const float* __restrict__ b_ih, const float* __restrict__ b_hh,
    const float* __restrict__ W_out,  // [64,128]
    const float* __restrict__ b_out,  // [64]
    float* __restrict__ out)          // [BS,64]
{
    const int j    = threadIdx.x;       // gate index 0..511
    const int row0 = blockIdx.x * 8;
    const int r2   = j >> 6;            // phase-2 row 0..7
    const int m    = j & 63;            // phase-2 elem 0..63 (and m+64)

    const float4* ip = (const float4*)&W_ih[j * 64];
    LD16(ip, wi)
    const float4* hp = (const float4*)&W_hh[j * 128];
    LD32(hp, wh)

    const float bias = b_ih[j] + b_hh[j];

    __shared__ float s_x[8][64];    // staged ctx slice
    __shared__ float s_h[8][128];   // hidden state
    __shared__ float s_g[8][512];   // pre-activation gates

    float c0 = 0.f, c1 = 0.f;       // cell state for (r2,m) and (r2,m+64)

    for (int s = 0; s < SEQ; ++s) {
        // stage x for this step (coalesced: 64 consecutive floats per row)
        s_x[r2][m] = ctx[((row0 + r2) * SEQ + s) * 64 + m];
        __syncthreads();

        float a0=bias, a1=bias, a2=bias, a3=bias, a4=bias, a5=bias, a6=bias, a7=bias;

        DOT16(a0, XP(0), wi)
        DOT16(a1, XP(1), wi)
        DOT16(a2, XP(2), wi)
        DOT16(a3, XP(3), wi)
        DOT16(a4, XP(4), wi)
        DOT16(a5, XP(5), wi)
        DOT16(a6, XP(6), wi)
        DOT16(a7, XP(7), wi)

        if (s > 0) {
            DOT32(a0, HP(0), wh)
            DOT32(a1, HP(1), wh)
            DOT32(a2, HP(2), wh)
            DOT32(a3, HP(3), wh)
            DOT32(a4, HP(4), wh)
            DOT32(a5, HP(5), wh)
            DOT32(a6, HP(6), wh)
            DOT32(a7, HP(7), wh)
        }
        s_g[0][j]=a0; s_g[1][j]=a1; s_g[2][j]=a2; s_g[3][j]=a3;
        s_g[4][j]=a4; s_g[5][j]=a5; s_g[6][j]=a6; s_g[7][j]=a7;
        __syncthreads();

        // pointwise: i,f,g,o -> c,h for (r2,m) and (r2,m+64)
        {
            float i0 = sigf(s_g[r2][m]);
            float f0 = sigf(s_g[r2][128 + m]);
            float g0 = tanhfast(s_g[r2][256 + m]);
            float o0 = sigf(s_g[r2][384 + m]);
            c0 = fmaf(f0, c0, i0 * g0);
            s_h[r2][m] = o0 * tanhfast(c0);

            float i1 = sigf(s_g[r2][64 + m]);
            float f1 = sigf(s_g[r2][192 + m]);
            float g1 = tanhfast(s_g[r2][320 + m]);
            float o1 = sigf(s_g[r2][448 + m]);
            c1 = fmaf(f1, c1, i1 * g1);
            s_h[r2][m + 64] = o1 * tanhfast(c1);
        }
        __syncthreads();
    }

    // final projection: out[row0+r2][m] = b_out[m] + h . W_out[m]
    float acco = b_out[m];
    {
        const float4* hq = (const float4*)&s_h[r2][0];
        const float4* wp = (const float4*)&W_out[m * 128];
        #pragma unroll
        for (int kk = 0; kk < 32; ++kk) {
            float4 h4 = hq[kk];
            float4 w4 = wp[kk];
            acco = fmaf(h4.x, w4.x, acco);
            acco = fmaf(h4.y, w4.y, acco);
            acco = fmaf(h4.z, w4.z, acco);
            acco = fmaf(h4.w, w4.w, acco);
        }
    }
    out[(row0 + r2) * 64 + m] = acco;
}

// ---------------------------------------------------------------------------
extern "C" void kernel_launch(void* const* d_in, const int* in_sizes, int n_in,
                              void* d_out, int out_size, void* d_ws, size_t ws_size,
                              hipStream_t stream) {
    (void)in_sizes; (void)n_in; (void)out_size; (void)ws_size;
    const float* seqs  = (const float*)d_in[0];
    const float* ets   = (const float*)d_in[1];
    const int*   masks = (const int*)d_in[2];
    const float* Wf  = (const float*)d_in[3];
    const float* bf  = (const float*)d_in[4];
    const float* Wk  = (const float*)d_in[5];
    const float* bk  = (const float*)d_in[6];
    const float* Wq  = (const float*)d_in[7];
    const float* bq  = (const float*)d_in[8];
    const float* Wv  = (const float*)d_in[9];
    const float* bv  = (const float*)d_in[10];
    const float* Wih = (const float*)d_in[11];
    const float* Whh = (const float*)d_in[12];
    const float* bih = (const float*)d_in[13];
    const float* bhh = (const float*)d_in[14];
    const float* Wo  = (const float*)d_in[15];
    const float* bo  = (const float*)d_in[16];

    float* ctx = (float*)d_ws;  // [BS,SEQ,64] fp32 = 26.2 MB

    hipLaunchKernelGGL(edge_attn_ctx, dim3(4096), dim3(64), 0, stream,
                       seqs, ets, masks, Wf, bf, Wk, bk, Wq, bq, Wv, bv, ctx);
    hipLaunchKernelGGL(lstm_out, dim3(256), dim3(512), 0, stream,
                       ctx, Wih, Whh, bih, bhh, Wo, bo, (float*)d_out);
}

// Round 6
// 1044.414 us; speedup vs baseline: 3.0774x; 2.6375x over previous
//
#include <hip/hip_runtime.h>
#include <math.h>

#define BS   2048
#define SEQ  50
#define NPOS (BS * SEQ)

__device__ __forceinline__ float sigf(float x) { return 1.0f / (1.0f + __expf(-x)); }
__device__ __forceinline__ float tanhfast(float x) {
    float e = __expf(2.0f * x);
    return 1.0f - 2.0f / (e + 1.0f);
}

// ---- macro toolkit: named-SSA values only (NO private arrays) -------------
#define FMA4(A, X, W) \
    A = fmaf((X).x, (W).x, A); A = fmaf((X).y, (W).y, A); \
    A = fmaf((X).z, (W).z, A); A = fmaf((X).w, (W).w, A);

#define LD16(P, N) \
    float4 N##0=(P)[0],  N##1=(P)[1],  N##2=(P)[2],  N##3=(P)[3], \
           N##4=(P)[4],  N##5=(P)[5],  N##6=(P)[6],  N##7=(P)[7], \
           N##8=(P)[8],  N##9=(P)[9],  N##10=(P)[10],N##11=(P)[11], \
           N##12=(P)[12],N##13=(P)[13],N##14=(P)[14],N##15=(P)[15];

#define LD8(P, N) \
    float4 N##0=(P)[0], N##1=(P)[1], N##2=(P)[2], N##3=(P)[3], \
           N##4=(P)[4], N##5=(P)[5], N##6=(P)[6], N##7=(P)[7];

// ---------------------------------------------------------------------------
// Kernel A: unchanged from R5 (this round isolates the lstm change).
// ---------------------------------------------------------------------------
__global__
__attribute__((amdgpu_flat_work_group_size(64, 64), amdgpu_waves_per_eu(2, 2)))
void edge_attn_ctx(
    const float* __restrict__ seqs,   // [BS,SEQ,3,3,6]
    const float* __restrict__ ets,    // [BS,SEQ,3,3,4]
    const int*   __restrict__ masks,  // [BS,SEQ,3,3]
    const float* __restrict__ Wf, const float* __restrict__ bf,  // [64,19],[64]
    const float* __restrict__ Wk, const float* __restrict__ bk,  // [64,6],[64]
    const float* __restrict__ Wq, const float* __restrict__ bq,  // [64,64],[64]
    const float* __restrict__ Wv, const float* __restrict__ bv,  // [64,64],[64]
    float* __restrict__ ctx)          // [BS,SEQ,64]
{
    const int o = threadIdx.x;

    const float4* qp = (const float4*)&Wq[o * 64];
    LD16(qp, wq)
    const float4* vp = (const float4*)&Wv[o * 64];
    LD16(vp, wv)

    const float* wfp = &Wf[o * 19];
    float wf0=wfp[0], wf1=wfp[1], wf2=wfp[2], wf3=wfp[3], wf4=wfp[4], wf5=wfp[5],
          wf6=wfp[6], wf7=wfp[7], wf8=wfp[8], wf9=wfp[9];
    float wfe0=wfp[10], wfe1=wfp[11], wfe2=wfp[12], wfe3=wfp[13], wfe4=wfp[14],
          wfe5=wfp[15], wfe6=wfp[16], wfe7=wfp[17], wfe8=wfp[18];
    const float* wkp = &Wk[o * 6];
    float wk0=wkp[0], wk1=wkp[1], wk2=wkp[2], wk3=wkp[3], wk4=wkp[4], wk5=wkp[5];

    const float bfr = bf[o], bkr = bk[o], bqr = bq[o], bvr = bv[o];

    __shared__ float s_seq[54];
    __shared__ float s_et[36];
    __shared__ int   s_mask[9];
    __shared__ float s_edge[9 * 64];

    for (int p = blockIdx.x; p < NPOS; p += gridDim.x) {
        if (o < 54) s_seq[o]  = seqs[p * 54 + o];
        if (o < 36) s_et[o]   = ets[p * 36 + o];
        if (o < 9)  s_mask[o] = masks[p * 9 + o];
        __syncthreads();

        float wfe[9] = {wfe0,wfe1,wfe2,wfe3,wfe4,wfe5,wfe6,wfe7,wfe8};
        #pragma unroll
        for (int e = 0; e < 9; ++e) {
            float v = bfr + wfe[e];
            v = fmaf(s_seq[e*6+0], wf0, v);
            v = fmaf(s_seq[e*6+1], wf1, v);
            v = fmaf(s_seq[e*6+2], wf2, v);
            v = fmaf(s_seq[e*6+3], wf3, v);
            v = fmaf(s_seq[e*6+4], wf4, v);
            v = fmaf(s_seq[e*6+5], wf5, v);
            v = fmaf(s_et[e*4+0],  wf6, v);
            v = fmaf(s_et[e*4+1],  wf7, v);
            v = fmaf(s_et[e*4+2],  wf8, v);
            v = fmaf(s_et[e*4+3],  wf9, v);
            s_edge[e * 64 + o] = v;
        }
        float key = bkr;
        key = fmaf(s_seq[24], wk0, key);
        key = fmaf(s_seq[25], wk1, key);
        key = fmaf(s_seq[26], wk2, key);
        key = fmaf(s_seq[27], wk3, key);
        key = fmaf(s_seq[28], wk4, key);
        key = fmaf(s_seq[29], wk5, key);
        __syncthreads();

        float vv[9], att[9];
        #pragma unroll
        for (int e = 0; e < 9; ++e) {
            const float4* ep = (const float4*)&s_edge[e * 64];
            float q = 0.f, v = 0.f;
            {
                float4 t;
                t=ep[0];  FMA4(q,t,wq0)  FMA4(v,t,wv0)
                t=ep[1];  FMA4(q,t,wq1)  FMA4(v,t,wv1)
                t=ep[2];  FMA4(q,t,wq2)  FMA4(v,t,wv2)
                t=ep[3];  FMA4(q,t,wq3)  FMA4(v,t,wv3)
                t=ep[4];  FMA4(q,t,wq4)  FMA4(v,t,wv4)
                t=ep[5];  FMA4(q,t,wq5)  FMA4(v,t,wv5)
                t=ep[6];  FMA4(q,t,wq6)  FMA4(v,t,wv6)
                t=ep[7];  FMA4(q,t,wq7)  FMA4(v,t,wv7)
                t=ep[8];  FMA4(q,t,wq8)  FMA4(v,t,wv8)
                t=ep[9];  FMA4(q,t,wq9)  FMA4(v,t,wv9)
                t=ep[10]; FMA4(q,t,wq10) FMA4(v,t,wv10)
                t=ep[11]; FMA4(q,t,wq11) FMA4(v,t,wv11)
                t=ep[12]; FMA4(q,t,wq12) FMA4(v,t,wv12)
                t=ep[13]; FMA4(q,t,wq13) FMA4(v,t,wv13)
                t=ep[14]; FMA4(q,t,wq14) FMA4(v,t,wv14)
                t=ep[15]; FMA4(q,t,wq15) FMA4(v,t,wv15)
            }
            float qq = bqr + q;
            vv[e] = bvr + v;
            float a_ = key * qq;
            a_ += __shfl_xor(a_, 8, 16);
            a_ += __shfl_xor(a_, 4, 16);
            a_ += __shfl_xor(a_, 2, 16);
            a_ += __shfl_xor(a_, 1, 16);
            att[e] = a_ * 0.25f;   // / sqrt(16)
        }

        float mx = -3.0e38f;
        #pragma unroll
        for (int e = 0; e < 9; ++e) {
            att[e] = (s_mask[e] == 0) ? -1.0e10f : att[e];
            mx = fmaxf(mx, att[e]);
        }
        float ssum = 0.f;
        #pragma unroll
        for (int e = 0; e < 9; ++e) { att[e] = __expf(att[e] - mx); ssum += att[e]; }
        float inv = 1.f / ssum;
        float acc = 0.f;
        #pragma unroll
        for (int e = 0; e < 9; ++e) acc = fmaf(att[e], vv[e], acc);
        ctx[p * 64 + o] = acc * inv;
        __syncthreads();
    }
}

// ---------------------------------------------------------------------------
// Kernel C v4: fits the PROVEN 128-VGPR budget; no private residency beyond
// 64 regs of W_ih; W_hh streamed from global (L2-resident, shared by all
// blocks) instead of compiler spill-scratch (private -> HBM, R1-R5's 5-10 GB).
//   512 thr, 256 blk, 8 rows/block. t -> gate pair gg=t>>1, k-half kh=t&1.
//   Thread computes both gates of its pair on its k-half; pair-sum via
//   __shfl_xor(.,1); lane kh writes gate 2gg+kh. ds_read_b128 halved vs R3.
// ---------------------------------------------------------------------------
#define SX4(r) ((const float4*)&s_x[r][koff])
#define SH4(r) ((const float4*)&s_h[r][koff2])

#define XDOT(kk) { float4 x4_; \
    x4_ = SX4(0)[kk]; FMA4(aA0,x4_,wiA##kk) FMA4(aB0,x4_,wiB##kk) \
    x4_ = SX4(1)[kk]; FMA4(aA1,x4_,wiA##kk) FMA4(aB1,x4_,wiB##kk) \
    x4_ = SX4(2)[kk]; FMA4(aA2,x4_,wiA##kk) FMA4(aB2,x4_,wiB##kk) \
    x4_ = SX4(3)[kk]; FMA4(aA3,x4_,wiA##kk) FMA4(aB3,x4_,wiB##kk) \
    x4_ = SX4(4)[kk]; FMA4(aA4,x4_,wiA##kk) FMA4(aB4,x4_,wiB##kk) \
    x4_ = SX4(5)[kk]; FMA4(aA5,x4_,wiA##kk) FMA4(aB5,x4_,wiB##kk) \
    x4_ = SX4(6)[kk]; FMA4(aA6,x4_,wiA##kk) FMA4(aB6,x4_,wiB##kk) \
    x4_ = SX4(7)[kk]; FMA4(aA7,x4_,wiA##kk) FMA4(aB7,x4_,wiB##kk) }

#define HROW2(r, g) { float4 h0_, h1_; \
    h0_ = SH4(r)[2*(g)]; h1_ = SH4(r)[2*(g)+1]; \
    FMA4(aA##r,h0_,wa0_) FMA4(aA##r,h1_,wa1_) \
    FMA4(aB##r,h0_,wb0_) FMA4(aB##r,h1_,wb1_) }

#define HGRP(g) { \
    float4 wa0_=whAp[2*(g)], wa1_=whAp[2*(g)+1]; \
    float4 wb0_=whBp[2*(g)], wb1_=whBp[2*(g)+1]; \
    HROW2(0,g) HROW2(1,g) HROW2(2,g) HROW2(3,g) \
    HROW2(4,g) HROW2(5,g) HROW2(6,g) HROW2(7,g) }

#define REDW(r) { aA##r += __shfl_xor(aA##r, 1); aB##r += __shfl_xor(aB##r, 1); \
    s_g[r][t] = kh ? aB##r : aA##r; }

__global__ __launch_bounds__(512)
void lstm_out(
    const float* __restrict__ ctx,    // [BS,SEQ,64]
    const float* __restrict__ W_ih,   // [512,64]
    const float* __restrict__ W_hh,   // [512,128]
    const float* __restrict__ b_ih, const float* __restrict__ b_hh,
    const float* __restrict__ W_out,  // [64,128]
    const float* __restrict__ b_out,  // [64]
    float* __restrict__ out)          // [BS,64]
{
    const int t    = threadIdx.x;
    const int gg   = t >> 1;          // gate pair 0..255
    const int kh   = t & 1;           // k-half
    const int jA   = gg * 2, jB = jA + 1;
    const int row0 = blockIdx.x * 8;
    const int r2   = t >> 6;          // pointwise row 0..7
    const int m    = t & 63;          // pointwise elem (and m+64)
    const int koff = kh * 32;         // x k-half offset (floats)
    const int koff2= kh * 64;         // h k-half offset (floats)

    // resident W_ih half-rows for both gates: 16 float4 = 64 VGPR
    const float4* wiAp = (const float4*)&W_ih[jA * 64 + koff];
    LD8(wiAp, wiA)
    const float4* wiBp = (const float4*)&W_ih[jB * 64 + koff];
    LD8(wiBp, wiB)

    // W_hh stream bases (L2-resident; 384 KB total shared chip-wide)
    const float4* whAp = (const float4*)&W_hh[jA * 128 + koff2];
    const float4* whBp = (const float4*)&W_hh[jB * 128 + koff2];

    // pointwise biases (gate order i,f,g,o = rows 0/128/256/384)
    const float bi0 = b_ih[m]       + b_hh[m];
    const float bf0 = b_ih[128 + m] + b_hh[128 + m];
    const float bg0 = b_ih[256 + m] + b_hh[256 + m];
    const float bo0 = b_ih[384 + m] + b_hh[384 + m];
    const float bi1 = b_ih[64 + m]  + b_hh[64 + m];
    const float bf1 = b_ih[192 + m] + b_hh[192 + m];
    const float bg1 = b_ih[320 + m] + b_hh[320 + m];
    const float bo1 = b_ih[448 + m] + b_hh[448 + m];

    __shared__ float s_x[8][64];
    __shared__ float s_h[8][128];
    __shared__ float s_g[8][512];

    float c0 = 0.f, c1 = 0.f;

    for (int s = 0; s < SEQ; ++s) {
        s_x[r2][m] = ctx[((row0 + r2) * SEQ + s) * 64 + m];
        __syncthreads();

        float aA0=0.f,aA1=0.f,aA2=0.f,aA3=0.f,aA4=0.f,aA5=0.f,aA6=0.f,aA7=0.f;
        float aB0=0.f,aB1=0.f,aB2=0.f,aB3=0.f,aB4=0.f,aB5=0.f,aB6=0.f,aB7=0.f;

        XDOT(0) XDOT(1) XDOT(2) XDOT(3) XDOT(4) XDOT(5) XDOT(6) XDOT(7)

        if (s > 0) {
            HGRP(0) HGRP(1) HGRP(2) HGRP(3)
            HGRP(4) HGRP(5) HGRP(6) HGRP(7)
        }

        REDW(0) REDW(1) REDW(2) REDW(3) REDW(4) REDW(5) REDW(6) REDW(7)
        __syncthreads();

        // pointwise for (r2, m) and (r2, m+64); c-state in registers
        {
            float ig = sigf(s_g[r2][m] + bi0);
            float fg = sigf(s_g[r2][128 + m] + bf0);
            float gt = tanhfast(s_g[r2][256 + m] + bg0);
            float og = sigf(s_g[r2][384 + m] + bo0);
            c0 = fmaf(fg, c0, ig * gt);
            s_h[r2][m] = og * tanhfast(c0);

            float ih = sigf(s_g[r2][64 + m] + bi1);
            float fh = sigf(s_g[r2][192 + m] + bf1);
            float gh = tanhfast(s_g[r2][320 + m] + bg1);
            float oh = sigf(s_g[r2][448 + m] + bo1);
            c1 = fmaf(fh, c1, ih * gh);
            s_h[r2][m + 64] = oh * tanhfast(c1);
        }
        __syncthreads();
    }

    // epilogue: out[row0+r2][m] = b_out[m] + h[r2] . W_out[m]
    float acco = b_out[m];
    {
        const float4* hq = (const float4*)&s_h[r2][0];
        const float4* wp = (const float4*)&W_out[m * 128];
        #pragma unroll
        for (int kk = 0; kk < 32; ++kk) {
            float4 h4 = hq[kk];
            float4 w4 = wp[kk];
            FMA4(acco, h4, w4)
        }
    }
    out[(row0 + r2) * 64 + m] = acco;
}

// ---------------------------------------------------------------------------
extern "C" void kernel_launch(void* const* d_in, const int* in_sizes, int n_in,
                              void* d_out, int out_size, void* d_ws, size_t ws_size,
                              hipStream_t stream) {
    (void)in_sizes; (void)n_in; (void)out_size; (void)ws_size;
    const float* seqs  = (const float*)d_in[0];
    const float* ets   = (const float*)d_in[1];
    const int*   masks = (const int*)d_in[2];
    const float* Wf  = (const float*)d_in[3];
    const float* bf  = (const float*)d_in[4];
    const float* Wk  = (const float*)d_in[5];
    const float* bk  = (const float*)d_in[6];
    const float* Wq  = (const float*)d_in[7];
    const float* bq  = (const float*)d_in[8];
    const float* Wv  = (const float*)d_in[9];
    const float* bv  = (const float*)d_in[10];
    const float* Wih = (const float*)d_in[11];
    const float* Whh = (const float*)d_in[12];
    const float* bih = (const float*)d_in[13];
    const float* bhh = (const float*)d_in[14];
    const float* Wo  = (const float*)d_in[15];
    const float* bo  = (const float*)d_in[16];

    float* ctx = (float*)d_ws;  // [BS,SEQ,64] fp32 = 26.2 MB

    hipLaunchKernelGGL(edge_attn_ctx, dim3(4096), dim3(64), 0, stream,
                       seqs, ets, masks, Wf, bf, Wk, bk, Wq, bq, Wv, bv, ctx);
    hipLaunchKernelGGL(lstm_out, dim3(256), dim3(512), 0, stream,
                       ctx, Wih, Whh, bih, bhh, Wo, bo, (float*)d_out);
}